// Round 16
// baseline (60.026 us; speedup 1.0000x reference)
//
#include <hip/hip_runtime.h>
#include <math.h>

#define GRID     64
#define NCELLS   (GRID * GRID)        // 4096 cells, 8x8 px each
#define INV_CELL 0.125f
#define CELLSZ   8.0f
#define NBLK     256
#define NTHR     256

__device__ __forceinline__ int clampi(int v, int lo, int hi) {
    return v < lo ? lo : (v > hi ? hi : v);
}
__device__ __forceinline__ int cell_of(float x, float y) {
    const int cx = clampi((int)(x * INV_CELL), 0, GRID - 1);
    const int cy = clampi((int)(y * INV_CELL), 0, GRID - 1);
    return cy * GRID + cx;
}

// Grid barrier: monotonic counting (goal = phase * NBLK), no reset needed
// within a launch; bar[0] zeroed by hipMemsetAsync each launch. Safe because
// all NBLK blocks are co-resident (17 KB LDS, 256 thr -> >=8 blocks/CU).
__device__ __forceinline__ void gbar(int* bar, int goal) {
    __syncthreads();
    if (threadIdx.x == 0) {
        __threadfence();                                   // release
        atomicAdd(bar, 1);
        while (__hip_atomic_load(bar, __ATOMIC_RELAXED,
                                 __HIP_MEMORY_SCOPE_AGENT) < goal) {
            __builtin_amdgcn_s_sleep(2);
        }
        __threadfence();                                   // acquire
    }
    __syncthreads();
}

__device__ __forceinline__ float scan_range(
    const float2* __restrict__ tb, int s, int e,
    float qx, float qy, float best)
{
    for (int k = s; k < e; ++k) {
        float2 v = tb[k];
        float dx = qx - v.x, dy = qy - v.y;
        best = fminf(best, fmaf(dx, dx, dy * dy));
    }
    return best;
}

// ONE persistent kernel, 3 phases over 2 grid barriers:
//  A: blocks 0,1 = per-set LDS hist + scan (write start+cur);
//     blocks 2..  = preload scatter point into regs; block2 zeroes out.
//  B: scatter via global atomic cursors.
//  C: search, 2 lanes/query (row-ranges split in half, shfl-combined),
//     ring fallback exact; block partial sums -> atomicAdd(out).
__global__ __launch_bounds__(NTHR) void chamfer_fused(
    const float2* __restrict__ p, int np,
    const float2* __restrict__ q, int nq,
    int* __restrict__ startP, int* __restrict__ startQ,
    int* __restrict__ curP, int* __restrict__ curQ,
    float2* __restrict__ binP, float2* __restrict__ binQ,
    int* __restrict__ bar, float* __restrict__ out)
{
    const int bid = blockIdx.x, t = threadIdx.x;
    const int total = np + nq;

    __shared__ int hist[NCELLS];
    __shared__ int ls[NTHR];
    __shared__ float red[4];

    // ---------------- Phase A ----------------
    float2 myv = make_float2(0.f, 0.f);
    int    myc = -1;
    if (bid >= 2) {
        const int stid = (bid - 2) * NTHR + t;
        if (stid < total) {
            myv = (stid < np) ? p[stid] : q[stid - np];
            myc = cell_of(myv.x, myv.y);
        }
        if (bid == 2 && t == 0) out[0] = 0.f;
    } else {
        const float2* __restrict__ pts = bid ? q : p;
        const int n = bid ? nq : np;
        int* __restrict__ start = bid ? startQ : startP;
        int* __restrict__ cur   = bid ? curQ : curP;

        for (int k = t; k < NCELLS; k += NTHR) hist[k] = 0;
        __syncthreads();

        const float4* __restrict__ pts4 = (const float4*)pts;
        const int n2 = n >> 1;                 // n even (16384)
        int i = t;
        for (; i + 3 * NTHR < n2; i += 4 * NTHR) {   // 4 outstanding loads
            float4 v0 = pts4[i];
            float4 v1 = pts4[i + NTHR];
            float4 v2 = pts4[i + 2 * NTHR];
            float4 v3 = pts4[i + 3 * NTHR];
            atomicAdd(&hist[cell_of(v0.x, v0.y)], 1);
            atomicAdd(&hist[cell_of(v0.z, v0.w)], 1);
            atomicAdd(&hist[cell_of(v1.x, v1.y)], 1);
            atomicAdd(&hist[cell_of(v1.z, v1.w)], 1);
            atomicAdd(&hist[cell_of(v2.x, v2.y)], 1);
            atomicAdd(&hist[cell_of(v2.z, v2.w)], 1);
            atomicAdd(&hist[cell_of(v3.x, v3.y)], 1);
            atomicAdd(&hist[cell_of(v3.z, v3.w)], 1);
        }
        for (; i < n2; i += NTHR) {
            float4 v = pts4[i];
            atomicAdd(&hist[cell_of(v.x, v.y)], 1);
            atomicAdd(&hist[cell_of(v.z, v.w)], 1);
        }
        __syncthreads();

        // exclusive scan: 16 cells/thread + 256-wide LDS scan
        const int base = t * 16;
        int loc[16], s = 0;
        #pragma unroll
        for (int k = 0; k < 16; ++k) { loc[k] = hist[base + k]; s += loc[k]; }
        ls[t] = s; __syncthreads();
        for (int off = 1; off < NTHR; off <<= 1) {
            int v = (t >= off) ? ls[t - off] : 0;
            __syncthreads();
            ls[t] += v;
            __syncthreads();
        }
        int ex = ls[t] - s;
        #pragma unroll
        for (int k = 0; k < 16; ++k) {
            start[base + k] = ex; cur[base + k] = ex; ex += loc[k];
        }
        if (t == 0) start[NCELLS] = n;
    }
    gbar(bar, NBLK);

    // ---------------- Phase B: scatter ----------------
    if (myc >= 0) {
        const int stid = (bid - 2) * NTHR + t;
        if (stid < np) binP[atomicAdd(&curP[myc], 1)] = myv;
        else           binQ[atomicAdd(&curQ[myc], 1)] = myv;
    }
    gbar(bar, 2 * NBLK);

    // ---------------- Phase C: search ----------------
    const int qid = (bid * NTHR + t) >> 1;   // 2 lanes per query
    const int sub = t & 1;
    float d = 0.f;
    if (qid < total) {
        const bool sideP = (qid < np);
        const float2 qry = sideP ? binP[qid] : binQ[qid - np];
        const float2* __restrict__ tb = sideP ? binQ : binP;
        const int*    __restrict__ ts = sideP ? startQ : startP;
        const int cx = clampi((int)(qry.x * INV_CELL), 0, GRID - 1);
        const int cy = clampi((int)(qry.y * INV_CELL), 0, GRID - 1);
        float best = 3.0e38f;

        // fused 3x3 (rings 0+1): 3 contiguous ranges, each split across the
        // lane pair; combine with shfl_xor.
        const int x0 = max(cx - 1, 0), x1 = min(cx + 1, GRID - 1);
        const int y0 = max(cy - 1, 0), y1 = min(cy + 1, GRID - 1);
        for (int y = y0; y <= y1; ++y) {
            const int rb = y * GRID;
            const int s = ts[rb + x0], e = ts[rb + x1 + 1];
            const int mid = (s + e) >> 1;
            best = scan_range(tb, sub ? mid : s, sub ? e : mid,
                              qry.x, qry.y, best);
        }
        best = fminf(best, __shfl_xor(best, 1));

        if (best > CELLSZ * CELLSZ) {   // rare: both lanes run identically
            for (int r = 2; r < GRID; ++r) {
                const int xa = max(cx - r, 0), xb = min(cx + r, GRID - 1);
                const int yT = cy - r, yB = cy + r;
                if (yT >= 0)
                    best = scan_range(tb, ts[yT * GRID + xa],
                                      ts[yT * GRID + xb + 1], qry.x, qry.y, best);
                if (yB < GRID)
                    best = scan_range(tb, ts[yB * GRID + xa],
                                      ts[yB * GRID + xb + 1], qry.x, qry.y, best);
                const int ya = max(cy - r + 1, 0), yb = min(cy + r - 1, GRID - 1);
                for (int y = ya; y <= yb; ++y) {
                    if (cx - r >= 0) {
                        const int c = y * GRID + cx - r;
                        best = scan_range(tb, ts[c], ts[c + 1], qry.x, qry.y, best);
                    }
                    if (cx + r < GRID) {
                        const int c = y * GRID + cx + r;
                        best = scan_range(tb, ts[c], ts[c + 1], qry.x, qry.y, best);
                    }
                }
                const float bnd = (float)r * CELLSZ;
                if (best <= bnd * bnd) break;
            }
        }
        if (sub == 0) d = sqrtf(fmaxf(best, 0.f));
    }

    #pragma unroll
    for (int off = 32; off > 0; off >>= 1) d += __shfl_down(d, off);
    if ((t & 63) == 0) red[t >> 6] = d;
    __syncthreads();
    if (t == 0) atomicAdd(out, (red[0] + red[1]) + (red[2] + red[3]));
}

extern "C" void kernel_launch(void* const* d_in, const int* in_sizes, int n_in,
                              void* d_out, int out_size, void* d_ws, size_t ws_size,
                              hipStream_t stream) {
    const float2* p = (const float2*)d_in[0];   // (16384, 2) f32
    const float2* q = (const float2*)d_in[1];   // (16384, 2) f32
    const int N = in_sizes[0] / 2;
    const int M = in_sizes[1] / 2;
    float* out = (float*)d_out;

    // ws layout
    int* bar     = (int*)d_ws;                      // 1 (zeroed per launch)
    int* startP  = bar + 4;                         // NCELLS+1
    int* startQ  = startP + NCELLS + 1;             // NCELLS+1
    int* curP    = startQ + NCELLS + 1;             // NCELLS
    int* curQ    = curP + NCELLS;                   // NCELLS
    float2* binP = (float2*)(curQ + NCELLS + 2);    // N entries (8B aligned)
    float2* binQ = binP + N;                        // M entries

    hipMemsetAsync(bar, 0, sizeof(int), stream);

    hipLaunchKernelGGL(chamfer_fused, dim3(NBLK), dim3(NTHR), 0, stream,
                       p, N, q, M, startP, startQ, curP, curQ,
                       binP, binQ, bar, out);
}

// Round 17
// 23.414 us; speedup vs baseline: 2.5637x; 2.5637x over previous
//
#include <hip/hip_runtime.h>
#include <math.h>

#define GRID     64
#define NCELLS   (GRID * GRID)        // 4096 cells, 8x8 px each
#define INV_CELL 0.125f
#define CELLSZ   8.0f

__device__ __forceinline__ int clampi(int v, int lo, int hi) {
    return v < lo ? lo : (v > hi ? hi : v);
}
__device__ __forceinline__ int cell_of(float x, float y) {
    const int cx = clampi((int)(x * INV_CELL), 0, GRID - 1);
    const int cy = clampi((int)(y * INV_CELL), 0, GRID - 1);
    return cy * GRID + cx;
}

// K1 (2 blocks x 512 thr, one block per set): LDS hist + scan, fused.
__global__ __launch_bounds__(512) void chamfer_setup2(
    const float2* __restrict__ p, int np,
    const float2* __restrict__ q, int nq,
    int* __restrict__ startP, int* __restrict__ startQ,
    int* __restrict__ curP, int* __restrict__ curQ,
    float* __restrict__ out)
{
    const int side = blockIdx.x;           // 0 -> P, 1 -> Q
    const float2* __restrict__ pts = side ? q : p;
    const int n = side ? nq : np;
    int* __restrict__ start = side ? startQ : startP;
    int* __restrict__ cur   = side ? curQ : curP;

    __shared__ int hist[NCELLS];
    __shared__ int ls[512];
    const int t = threadIdx.x;
    if (side == 0 && t == 0) out[0] = 0.f;
    for (int k = t; k < NCELLS; k += 512) hist[k] = 0;
    __syncthreads();

    // histogram: float4 = 2 points per load, 4 outstanding loads
    const float4* __restrict__ pts4 = (const float4*)pts;
    const int n2 = n >> 1;                 // n is even (16384)
    int i = t;
    for (; i + 3 * 512 < n2; i += 4 * 512) {
        float4 v0 = pts4[i];
        float4 v1 = pts4[i + 512];
        float4 v2 = pts4[i + 2 * 512];
        float4 v3 = pts4[i + 3 * 512];
        atomicAdd(&hist[cell_of(v0.x, v0.y)], 1);
        atomicAdd(&hist[cell_of(v0.z, v0.w)], 1);
        atomicAdd(&hist[cell_of(v1.x, v1.y)], 1);
        atomicAdd(&hist[cell_of(v1.z, v1.w)], 1);
        atomicAdd(&hist[cell_of(v2.x, v2.y)], 1);
        atomicAdd(&hist[cell_of(v2.z, v2.w)], 1);
        atomicAdd(&hist[cell_of(v3.x, v3.y)], 1);
        atomicAdd(&hist[cell_of(v3.z, v3.w)], 1);
    }
    for (; i < n2; i += 512) {
        float4 v = pts4[i];
        atomicAdd(&hist[cell_of(v.x, v.y)], 1);
        atomicAdd(&hist[cell_of(v.z, v.w)], 1);
    }
    __syncthreads();

    // exclusive scan: 8 cells/thread + 512-wide LDS scan
    const int base = t * 8;
    int loc[8], s = 0;
    #pragma unroll
    for (int k = 0; k < 8; ++k) { loc[k] = hist[base + k]; s += loc[k]; }
    ls[t] = s; __syncthreads();
    for (int off = 1; off < 512; off <<= 1) {
        int v = (t >= off) ? ls[t - off] : 0;
        __syncthreads();
        ls[t] += v;
        __syncthreads();
    }
    int ex = ls[t] - s;
    #pragma unroll
    for (int k = 0; k < 8; ++k) {
        start[base + k] = ex; cur[base + k] = ex; ex += loc[k];
    }
    if (t == 0) start[NCELLS] = n;
}

// K2: scatter (combined index; one point per thread). Bin order within a
// cell is atomic-order-dependent; downstream min is order-invariant.
__global__ __launch_bounds__(256) void chamfer_scatter(
    const float2* __restrict__ p, int np,
    const float2* __restrict__ q, int nq,
    int* __restrict__ curP, int* __restrict__ curQ,
    float2* __restrict__ binP, float2* __restrict__ binQ)
{
    const int i = blockIdx.x * 256 + threadIdx.x;
    if (i < np) {
        float2 v = p[i];
        binP[atomicAdd(&curP[cell_of(v.x, v.y)], 1)] = v;
    } else if (i < np + nq) {
        float2 v = q[i - np];
        binQ[atomicAdd(&curQ[cell_of(v.x, v.y)], 1)] = v;
    }
}

// K3: exact NN, FOUR lanes per query. Each lane scans stride-4 elements of
// each 3x3 row-range (quad reads consecutive float2s -> coalesced; chain/4),
// combined with 2x shfl_xor. After cheb ring r any unscanned cell is
// > r*8 px  =>  stop when best <= (8r)^2; fallback runs quad-redundant (rare).
__global__ __launch_bounds__(256) void chamfer_search(
    const float2* __restrict__ binP, int np,
    const float2* __restrict__ binQ, int nq,
    const int* __restrict__ startP, const int* __restrict__ startQ,
    float* __restrict__ out)
{
    const int tid = blockIdx.x * 256 + threadIdx.x;
    const int qid = tid >> 2;
    const int sub = tid & 3;
    const int total = np + nq;
    float d = 0.f;
    if (qid < total) {
        const bool sideP = (qid < np);
        const float2 qry = sideP ? binP[qid] : binQ[qid - np];
        const float2* __restrict__ tb = sideP ? binQ : binP;
        const int*    __restrict__ ts = sideP ? startQ : startP;
        const int cx = clampi((int)(qry.x * INV_CELL), 0, GRID - 1);
        const int cy = clampi((int)(qry.y * INV_CELL), 0, GRID - 1);
        float best = 3.0e38f;

        // fused 3x3 (rings 0+1): 3 contiguous ranges, strided across quad
        const int x0 = max(cx - 1, 0), x1 = min(cx + 1, GRID - 1);
        const int y0 = max(cy - 1, 0), y1 = min(cy + 1, GRID - 1);
        int sA[3], eA[3];
        #pragma unroll
        for (int k = 0; k < 3; ++k) {
            const int y = min(y0 + k, y1);       // clamp duplicates row
            sA[k] = ts[y * GRID + x0];
            eA[k] = ts[y * GRID + x1 + 1];
        }
        const int ny = y1 - y0 + 1;
        for (int r = 0; r < ny; ++r) {
            for (int k = sA[r] + sub; k < eA[r]; k += 4) {
                float2 v = tb[k];
                float dx = qry.x - v.x, dy = qry.y - v.y;
                best = fminf(best, fmaf(dx, dx, dy * dy));
            }
        }
        best = fminf(best, __shfl_xor(best, 1));
        best = fminf(best, __shfl_xor(best, 2));

        if (best > CELLSZ * CELLSZ) {   // rare: quad runs identical fallback
            for (int r = 2; r < GRID; ++r) {
                const int xa = max(cx - r, 0), xb = min(cx + r, GRID - 1);
                const int yT = cy - r, yB = cy + r;
                if (yT >= 0)
                    for (int k = ts[yT * GRID + xa]; k < ts[yT * GRID + xb + 1]; ++k) {
                        float2 v = tb[k];
                        float dx = qry.x - v.x, dy = qry.y - v.y;
                        best = fminf(best, fmaf(dx, dx, dy * dy));
                    }
                if (yB < GRID)
                    for (int k = ts[yB * GRID + xa]; k < ts[yB * GRID + xb + 1]; ++k) {
                        float2 v = tb[k];
                        float dx = qry.x - v.x, dy = qry.y - v.y;
                        best = fminf(best, fmaf(dx, dx, dy * dy));
                    }
                const int ya = max(cy - r + 1, 0), yb = min(cy + r - 1, GRID - 1);
                for (int y = ya; y <= yb; ++y) {
                    if (cx - r >= 0) {
                        const int c = y * GRID + cx - r;
                        for (int k = ts[c]; k < ts[c + 1]; ++k) {
                            float2 v = tb[k];
                            float dx = qry.x - v.x, dy = qry.y - v.y;
                            best = fminf(best, fmaf(dx, dx, dy * dy));
                        }
                    }
                    if (cx + r < GRID) {
                        const int c = y * GRID + cx + r;
                        for (int k = ts[c]; k < ts[c + 1]; ++k) {
                            float2 v = tb[k];
                            float dx = qry.x - v.x, dy = qry.y - v.y;
                            best = fminf(best, fmaf(dx, dx, dy * dy));
                        }
                    }
                }
                const float bnd = (float)r * CELLSZ;
                if (best <= bnd * bnd) break;
            }
        }
        if (sub == 0) d = sqrtf(fmaxf(best, 0.f));
    }

    #pragma unroll
    for (int off = 32; off > 0; off >>= 1) d += __shfl_down(d, off);
    __shared__ float s[4];
    if ((threadIdx.x & 63) == 0) s[threadIdx.x >> 6] = d;
    __syncthreads();
    if (threadIdx.x == 0) atomicAdd(out, (s[0] + s[1]) + (s[2] + s[3]));
}

extern "C" void kernel_launch(void* const* d_in, const int* in_sizes, int n_in,
                              void* d_out, int out_size, void* d_ws, size_t ws_size,
                              hipStream_t stream) {
    const float2* p = (const float2*)d_in[0];   // (16384, 2) f32
    const float2* q = (const float2*)d_in[1];   // (16384, 2) f32
    const int N = in_sizes[0] / 2;
    const int M = in_sizes[1] / 2;
    float* out = (float*)d_out;
    const int total = N + M;

    // ws layout
    int* startP  = (int*)d_ws;                      // NCELLS+1
    int* startQ  = startP + NCELLS + 1;             // NCELLS+1
    int* curP    = startQ + NCELLS + 1;             // NCELLS
    int* curQ    = curP + NCELLS;                   // NCELLS
    float2* binP = (float2*)(curQ + NCELLS + 2);    // N entries (8B aligned)
    float2* binQ = binP + N;                        // M entries

    hipLaunchKernelGGL(chamfer_setup2, dim3(2), dim3(512), 0, stream,
                       p, N, q, M, startP, startQ, curP, curQ, out);

    const int nbSc = (total + 255) / 256;
    hipLaunchKernelGGL(chamfer_scatter, dim3(nbSc), dim3(256), 0, stream,
                       p, N, q, M, curP, curQ, binP, binQ);

    const int nbS = (4 * total + 255) / 256;
    hipLaunchKernelGGL(chamfer_search, dim3(nbS), dim3(256), 0, stream,
                       binP, N, binQ, M, startP, startQ, out);
}